// Round 17
// baseline (64.551 us; speedup 1.0000x reference)
//
#include <hip/hip_runtime.h>
#include <hip/hip_bf16.h>

typedef short short8 __attribute__((ext_vector_type(8)));
typedef float f32x4 __attribute__((ext_vector_type(4)));
typedef float f32x16 __attribute__((ext_vector_type(16)));
typedef unsigned int uint4v __attribute__((ext_vector_type(4)));
typedef unsigned short ushort_t;

// ---------- bf16 helpers ----------
__device__ inline ushort_t f2bf(float f) {            // manual RNE
    union { float f; unsigned u; } x; x.f = f;
    unsigned r = x.u + 0x7fffu + ((x.u >> 16) & 1u);
    return (ushort_t)(r >> 16);
}
__device__ inline ushort_t f2bf_u(float x) {
    union { __hip_bfloat16 h; ushort_t u; } cv;
    cv.h = __float2bfloat16(x);
    return cv.u;
}
__device__ inline float bf2f(ushort_t u) {
    union { unsigned u; float f; } cv; cv.u = ((unsigned)u) << 16; return cv.f;
}

#define GLD_LDS16(src, dst)                                                  \
    __builtin_amdgcn_global_load_lds(                                        \
        (const __attribute__((address_space(1))) void*)(src),                \
        (__attribute__((address_space(3))) void*)(dst), 16, 0, 0)

// sqrt(SCALE * log2(e)); applied to r on both Q and K sides -> product = SCALE*log2(e)
#define RSQ 0.5050100f

// ---------- in-block weight transpose+convert: W[256 k][J] f32 slice ->
// LDS Wt[128 cols][256 k] bf16, XOR-chunk-swizzled ((col&7)<<4 on byte addr).
// Coalesced f32 reads (lanes = consecutive cols); one-time per block.
__device__ inline void stage_w(const float* __restrict__ W, int J, int cb,
                               ushort_t* lds, int tid) {
    const int c = tid & 127;            // local col 0..127
    const int kh = tid >> 7;            // k half: 0 or 1
    const float* src = W + (size_t)(kh * 128) * J + cb + c;
    #pragma unroll
    for (int kc = 0; kc < 16; ++kc) {   // 16 chunks of 8 k
        short8 tmp;
        #pragma unroll
        for (int m = 0; m < 8; ++m)
            tmp[m] = (short)f2bf(src[(size_t)(kc * 8 + m) * J]);
        int a0 = c * 512 + (kh * 128 + kc * 8) * 2;       // byte addr, 16B aligned
        int a = a0 ^ (((a0 >> 9) & 7) << 4);              // chunk swizzle (col&7)
        *reinterpret_cast<short8*>(reinterpret_cast<char*>(lds) + a) = tmp;
    }
}

// ---------- in-projection GEMM: A cached in VGPRs, 2 x 128-col sub-tiles ----------
// 256 blocks (64 x-tiles, y in {0=r-part cols 0..255, 1=v-part cols 256..511}, z=dir).
// A-fragments (64 rows x 256 k bf16) converted ONCE into 32 VGPRs/lane; B sub-tile
// (128 cols x 256 k) staged to 64KB LDS per iteration. Outputs (unit layouts):
//  rU [bh][unit((n>>5),kh,(d>>3)&1,(n&31))][e=d&7]: element = bf16(r[n][d] * RSQ)
//  vU [bh][unit((n>>5),vh,hi,d)][e]: element = v^T[d][kv], kv-permuted so that
//     e <-> kv = (n>>5)*32 + vh*16 + 4*hi + (e&3) + 8*(e>>2)
__global__ __launch_bounds__(256) void gemm_in_kernel(
    const float* __restrict__ A0, const float* __restrict__ A1,
    const float* __restrict__ W0, const float* __restrict__ W1,
    ushort_t* __restrict__ R0, ushort_t* __restrict__ R1,
    ushort_t* __restrict__ V0, ushort_t* __restrict__ V1) {
    __shared__ __align__(16) ushort_t bsm[32768];   // 64KB: [128 cols][256 k] bf16 swz
    const float* A = blockIdx.z ? A1 : A0;
    const float* W = blockIdx.z ? W1 : W0;
    ushort_t* R = blockIdx.z ? R1 : R0;
    ushort_t* Vt = blockIdx.z ? V1 : V0;
    constexpr int K = 256;
    const int w = threadIdx.x >> 6, lane = threadIdx.x & 63;
    const int l16 = lane & 15, g = lane >> 4;
    const int m0 = blockIdx.x * 64 + w * 16;

    // ---- convert this wave's A fragments once into registers (32 VGPRs) ----
    short8 aA[8];
    {
        const float* Ap = A + (size_t)(m0 + l16) * K + 8 * g;
        #pragma unroll
        for (int kc = 0; kc < 8; ++kc) {
            float4 af0 = *reinterpret_cast<const float4*>(Ap + kc * 32);
            float4 af1 = *reinterpret_cast<const float4*>(Ap + kc * 32 + 4);
            short8 a;
            a[0] = (short)f2bf_u(af0.x); a[1] = (short)f2bf_u(af0.y);
            a[2] = (short)f2bf_u(af0.z); a[3] = (short)f2bf_u(af0.w);
            a[4] = (short)f2bf_u(af1.x); a[5] = (short)f2bf_u(af1.y);
            a[6] = (short)f2bf_u(af1.z); a[7] = (short)f2bf_u(af1.w);
            aA[kc] = a;
        }
    }

    const int xorv = (l16 & 7) << 4;
    const char* bsb = reinterpret_cast<const char*>(bsm);

    #pragma unroll
    for (int it = 0; it < 2; ++it) {
        const int cb = blockIdx.y * 256 + it * 128;
        if (it) __syncthreads();                 // all waves done reading previous B
        stage_w(W, 512, cb, bsm, threadIdx.x);
        __syncthreads();

        f32x4 acc[8] = {};
        #pragma unroll
        for (int kc = 0; kc < 8; ++kc) {
            #pragma unroll
            for (int c = 0; c < 8; ++c) {
                int a0 = (c * 16 + l16) * 512 + (kc * 32 + 8 * g) * 2;
                short8 b = *reinterpret_cast<const short8*>(bsb + (a0 ^ xorv));
                acc[c] = __builtin_amdgcn_mfma_f32_16x16x32_bf16(aA[kc], b, acc[c], 0, 0, 0);
            }
        }

        if (blockIdx.y == 0) {
            // r-part, unit layout, pre-scaled (cols cb..cb+127, all < 256)
            #pragma unroll
            for (int c = 0; c < 8; ++c) {
                int col = cb + c * 16 + l16;        // 0..255
                int h = col >> 5, d = col & 31;
                #pragma unroll
                for (int r = 0; r < 4; ++r) {
                    int row = m0 + 4 * g + r;
                    int bb = row >> 11, n = row & 2047;
                    size_t base = (size_t)(bb * 8 + h) * 65536;
                    int unit = ((n >> 5) * 4 + (d >> 4) * 2 + ((d >> 3) & 1)) * 32 + (n & 31);
                    R[base + (size_t)unit * 8 + (d & 7)] = f2bf_u(acc[c][r] * RSQ);
                }
            }
        } else {
            // v-part, permuted unit layout; 4 consecutive n -> contiguous e run
            #pragma unroll
            for (int c = 0; c < 8; ++c) {
                int colp = cb - 256 + c * 16 + l16; // 0..255
                int h = colp >> 5, d = colp & 31;
                int row = m0 + 4 * g;
                int bb = row >> 11, n = row & 2047;
                size_t base = (size_t)(bb * 8 + h) * 65536;
                int nl = n & 31;
                int vh = nl >> 4, r4 = nl & 15;
                int hi2 = (r4 >> 2) & 1;
                int e0 = (r4 & 3) + 4 * (r4 >> 3);
                int unit = ((n >> 5) * 4 + vh * 2 + hi2) * 32 + d;
                ushort4 s;
                s.x = f2bf_u(acc[c][0]); s.y = f2bf_u(acc[c][1]);
                s.z = f2bf_u(acc[c][2]); s.w = f2bf_u(acc[c][3]);
                *reinterpret_cast<ushort4*>(Vt + base + (size_t)unit * 8 + e0) = s;
            }
        }
    }
}

// ---------- flash attention: 32x32x16 MFMA, K+V LDS-staged, full 2048 kv per block ----------
// 256 blocks (XCD-bijective): stream(dir,bh) x 8 qblk. 8 waves/block, 32 q-rows/wave.
// 16 tiles x 128 kv, double-buffered; 4 compute steps + one __syncthreads per tile.
// Writes one partial acc (bf16) + l (f32) per q-row; normalized in gemm_out.
__global__ __launch_bounds__(512, 4) void attn_kernel(
    const ushort_t* __restrict__ rU_sed, const ushort_t* __restrict__ rU_doa,
    const ushort_t* __restrict__ vU_sed, const ushort_t* __restrict__ vU_doa,
    ushort_t* __restrict__ part,   // [stream*2048 + q][32 d] bf16
    float* __restrict__ lpart) {   // [stream*2048 + q] f32
    __shared__ __align__(16) ushort_t smem[16384];   // 2 bufs x (K 8KB | V 8KB)

    const int bid = blockIdx.x;                // 0..255
    const int xcd = bid & 7, i = bid >> 3;     // i 0..31
    const int stream = xcd * 4 + (i & 3);      // 0..31
    const int qblk = i >> 2;                   // 0..7
    const int dir = stream >> 4, bh = stream & 15;

    const ushort_t* rQ = dir ? rU_doa : rU_sed;
    const ushort_t* rK = dir ? rU_sed : rU_doa;
    const ushort_t* vV = dir ? vU_sed : vU_doa;

    const int tid = threadIdx.x;
    const int w = tid >> 6, lane = tid & 63;
    const int l31 = lane & 31, hi = lane >> 5;
    const size_t sB = (size_t)bh * 65536;
    const int qbase = qblk * 256 + w * 32;

    // Q B-frags (pre-scaled in gemm_in)
    const short8 qf0 = *reinterpret_cast<const short8*>(rQ + sB + (size_t)qbase * 32 + lane * 8);
    const short8 qf1 = *reinterpret_cast<const short8*>(rQ + sB + (size_t)qbase * 32 + 512 + lane * 8);

    const ushort_t* srcK = rK + sB + tid * 8;                // per-lane global source
    const ushort_t* srcV = vV + sB + tid * 8;
    const int dstK = w * 512;                                // wave-uniform LDS base
    const int dstV = 4096 + w * 512;

    f32x16 acc = {};
    f32x4 lv = {};

    auto stage = [&](int t, int bufsel) {
        GLD_LDS16(srcK + (size_t)t * 4096, &smem[bufsel * 8192 + dstK]);
        GLD_LDS16(srcV + (size_t)t * 4096, &smem[bufsel * 8192 + dstV]);
    };

    int buf = 0;
    stage(0, 0);
    __syncthreads();

    for (int t = 0; t < 16; ++t) {             // 16 tiles x 128 kv = full 2048
        if (t < 15) stage(t + 1, buf ^ 1);
        const ushort_t* KB = &smem[buf * 8192];
        const ushort_t* VB = &smem[buf * 8192 + 4096];
        #pragma unroll
        for (int s = 0; s < 4; ++s) {
            short8 kf0 = *reinterpret_cast<const short8*>(KB + s * 1024 + lane * 8);
            short8 kf1 = *reinterpret_cast<const short8*>(KB + s * 1024 + 512 + lane * 8);
            short8 vf0 = *reinterpret_cast<const short8*>(VB + s * 1024 + lane * 8);
            short8 vf1 = *reinterpret_cast<const short8*>(VB + s * 1024 + 512 + lane * 8);

            f32x16 z16 = {};
            f32x16 st = __builtin_amdgcn_mfma_f32_32x32x16_bf16(kf0, qf0, z16, 0, 0, 0);
            st = __builtin_amdgcn_mfma_f32_32x32x16_bf16(kf1, qf1, st, 0, 0, 0);

            float p[16];
            #pragma unroll
            for (int j = 0; j < 16; ++j) {
                p[j] = __builtin_amdgcn_exp2f(st[j]);
            }
            #pragma unroll
            for (int j = 0; j < 16; ++j) lv[j & 3] += p[j];

            unsigned pk[8];
            #pragma unroll
            for (int j = 0; j < 8; ++j) {
                asm("v_cvt_pk_bf16_f32 %0, %1, %2" : "=v"(pk[j]) : "v"(p[2 * j]), "v"(p[2 * j + 1]));
            }
            union { uint4v u; short8 s; } c1, c2;
            c1.u = uint4v{pk[0], pk[1], pk[2], pk[3]};
            c2.u = uint4v{pk[4], pk[5], pk[6], pk[7]};

            acc = __builtin_amdgcn_mfma_f32_32x32x16_bf16(vf0, c1.s, acc, 0, 0, 0);
            acc = __builtin_amdgcn_mfma_f32_32x32x16_bf16(vf1, c2.s, acc, 0, 0, 0);
        }
        __syncthreads();
        buf ^= 1;
    }

    // epilogue: l and partial acc
    float l = (lv[0] + lv[1]) + (lv[2] + lv[3]);
    l += __shfl_xor(l, 32);
    const int q = qbase + l31;
    const size_t prow = (size_t)stream * 2048 + q;
    if (lane < 32) lpart[prow] = l;
    ushort_t* pa = part + prow * 32;
    #pragma unroll
    for (int r = 0; r < 16; ++r) {
        int d = (r & 3) + 8 * (r >> 2) + 4 * hi;
        pa[d] = f2bf(acc[r]);
    }
}

// ---------- out-projection GEMM: fused W-transpose + normalize, 128-col tiles ----------
// A[row][k] = part(row, k) / l(row), built on the fly per k-chunk.
__global__ __launch_bounds__(256) void gemm_out_kernel(
    const ushort_t* __restrict__ part, const float* __restrict__ lpart,
    const float* __restrict__ W0, const float* __restrict__ W1,
    float* __restrict__ c0, float* __restrict__ c1,
    const float* __restrict__ bias0, const float* __restrict__ bias1) {
    __shared__ __align__(16) ushort_t bsm[32768];   // 64KB: [128 cols][256 k] bf16 swz
    const int z = blockIdx.z;
    const float* W = z ? W1 : W0;
    float* C = z ? c1 : c0;
    const float* bias = z ? bias1 : bias0;
    constexpr int N = 256;
    const int w = threadIdx.x >> 6, lane = threadIdx.x & 63;
    const int l16 = lane & 15, g = lane >> 4;
    const int m0 = blockIdx.x * 64 + w * 16;
    const int cb = blockIdx.y * 128;

    stage_w(W, 256, cb, bsm, threadIdx.x);
    __syncthreads();

    const int row = m0 + l16;
    const int bb = row >> 11, q = row & 2047;
    const int xorv = (l16 & 7) << 4;
    const char* bsb = reinterpret_cast<const char*>(bsm);

    f32x4 acc[8] = {};
    #pragma unroll
    for (int it = 0; it < 8; ++it) {           // it = head h, k-chunk base = it*32
        const int strm = z * 16 + bb * 8 + it;
        const size_t pr0 = (size_t)strm * 2048 + q;
        float inv = 1.0f / lpart[pr0];
        const ushort_t* p0 = part + pr0 * 32 + 8 * g;
        short8 pa = *reinterpret_cast<const short8*>(p0);
        short8 a;
        #pragma unroll
        for (int e = 0; e < 8; ++e) {
            a[e] = (short)f2bf_u(bf2f((ushort_t)pa[e]) * inv);
        }
        #pragma unroll
        for (int c = 0; c < 8; ++c) {
            int a0 = (c * 16 + l16) * 512 + (it * 32 + 8 * g) * 2;
            short8 b = *reinterpret_cast<const short8*>(bsb + (a0 ^ xorv));
            acc[c] = __builtin_amdgcn_mfma_f32_16x16x32_bf16(a, b, acc[c], 0, 0, 0);
        }
    }
    #pragma unroll
    for (int c = 0; c < 8; ++c) {
        int col = cb + c * 16 + l16;
        #pragma unroll
        for (int r = 0; r < 4; ++r) {
            int orow = m0 + 4 * g + r;
            C[(size_t)orow * N + col] = acc[c][r] + bias[col];
        }
    }
}

// ---------- launch ----------
extern "C" void kernel_launch(void* const* d_in, const int* in_sizes, int n_in,
                              void* d_out, int out_size, void* d_ws, size_t ws_size,
                              hipStream_t stream) {
    const float* x_sed     = (const float*)d_in[0];
    const float* x_doa     = (const float*)d_in[1];
    const float* W_sed_in  = (const float*)d_in[2];
    const float* W_doa_in  = (const float*)d_in[3];
    const float* W_sed_out = (const float*)d_in[4];
    const float* b_sed_out = (const float*)d_in[5];
    const float* W_doa_out = (const float*)d_in[6];
    const float* b_doa_out = (const float*)d_in[7];
    float* out = (float*)d_out;

    ushort_t* ws = (ushort_t*)d_ws;
    ushort_t* rU_sed = ws;                          // 16*65536 (unit layout)
    ushort_t* rU_doa = rU_sed + 1048576;
    ushort_t* vU_sed = rU_doa + 1048576;            // 16*65536 (permuted unit layout)
    ushort_t* vU_doa = vU_sed + 1048576;
    ushort_t* part   = vU_doa + 1048576;            // 32*2048*32 bf16 = 4MB
    float*    lpart  = (float*)(part + 2097152);    // 32*2048 f32 = 256KB
    // total ~12.5 MB of ws

    gemm_in_kernel<<<dim3(64, 2, 2), 256, 0, stream>>>(x_sed, x_doa, W_sed_in, W_doa_in,
                                                       rU_sed, rU_doa, vU_sed, vU_doa);
    attn_kernel<<<dim3(256), 512, 0, stream>>>(rU_sed, rU_doa, vU_sed, vU_doa, part, lpart);
    gemm_out_kernel<<<dim3(64, 2, 2), 256, 0, stream>>>(part, lpart, W_sed_out, W_doa_out,
                                                        out, out + 1048576, b_sed_out, b_doa_out);
}

// Round 18
// 56.250 us; speedup vs baseline: 1.1476x; 1.1476x over previous
//
#include <hip/hip_runtime.h>
#include <hip/hip_bf16.h>

typedef short short8 __attribute__((ext_vector_type(8)));
typedef float f32x4 __attribute__((ext_vector_type(4)));
typedef float f32x16 __attribute__((ext_vector_type(16)));
typedef unsigned int uint4v __attribute__((ext_vector_type(4)));
typedef unsigned short ushort_t;

// ---------- bf16 helpers ----------
__device__ inline ushort_t f2bf(float f) {            // manual RNE
    union { float f; unsigned u; } x; x.f = f;
    unsigned r = x.u + 0x7fffu + ((x.u >> 16) & 1u);
    return (ushort_t)(r >> 16);
}
__device__ inline ushort_t f2bf_u(float x) {
    union { __hip_bfloat16 h; ushort_t u; } cv;
    cv.h = __float2bfloat16(x);
    return cv.u;
}
__device__ inline float bf2f(ushort_t u) {
    union { unsigned u; float f; } cv; cv.u = ((unsigned)u) << 16; return cv.f;
}

#define GLD_LDS16(src, dst)                                                  \
    __builtin_amdgcn_global_load_lds(                                        \
        (const __attribute__((address_space(1))) void*)(src),                \
        (__attribute__((address_space(3))) void*)(dst), 16, 0, 0)

// sqrt(SCALE * log2(e)); applied to r on both Q and K sides -> product = SCALE*log2(e)
#define RSQ 0.5050100f

// ---------- in-block weight transpose+convert: W[256 k][J] f32 slice ->
// LDS Wt[128 cols][256 k] bf16, XOR-chunk-swizzled ((col&7)<<4 on byte addr).
// Coalesced f32 reads (lanes = consecutive cols); one-time per block.
__device__ inline void stage_w(const float* __restrict__ W, int J, int cb,
                               ushort_t* lds, int tid) {
    const int c = tid & 127;            // local col 0..127
    const int kh = tid >> 7;            // k half: 0 or 1
    const float* src = W + (size_t)(kh * 128) * J + cb + c;
    #pragma unroll
    for (int kc = 0; kc < 16; ++kc) {   // 16 chunks of 8 k
        short8 tmp;
        #pragma unroll
        for (int m = 0; m < 8; ++m)
            tmp[m] = (short)f2bf(src[(size_t)(kc * 8 + m) * J]);
        int a0 = c * 512 + (kh * 128 + kc * 8) * 2;       // byte addr, 16B aligned
        int a = a0 ^ (((a0 >> 9) & 7) << 4);              // chunk swizzle (col&7)
        *reinterpret_cast<short8*>(reinterpret_cast<char*>(lds) + a) = tmp;
    }
}

// ---------- in-projection GEMM (fused W-transpose + f32->bf16 convert of A) ----------
// 128-col tiles. Outputs (unit layouts, 16B units):
//  rU [bh][unit((n>>5),kh,(d>>3)&1,(n&31))][e=d&7]: element = bf16(r[n][d] * RSQ)
//  vU [bh][unit((n>>5),vh,hi,d)][e]: element = v^T[d][kv], kv-permuted so that
//     e <-> kv = (n>>5)*32 + vh*16 + 4*hi + (e&3) + 8*(e>>2)
__global__ __launch_bounds__(256) void gemm_in_kernel(
    const float* __restrict__ A0, const float* __restrict__ A1,
    const float* __restrict__ W0, const float* __restrict__ W1,
    ushort_t* __restrict__ R0, ushort_t* __restrict__ R1,
    ushort_t* __restrict__ V0, ushort_t* __restrict__ V1) {
    __shared__ __align__(16) ushort_t bsm[32768];   // 64KB: [128 cols][256 k] bf16 swz
    const float* A = blockIdx.z ? A1 : A0;
    const float* W = blockIdx.z ? W1 : W0;
    ushort_t* R = blockIdx.z ? R1 : R0;
    ushort_t* Vt = blockIdx.z ? V1 : V0;
    constexpr int K = 256;
    const int w = threadIdx.x >> 6, lane = threadIdx.x & 63;
    const int l16 = lane & 15, g = lane >> 4;
    const int m0 = blockIdx.x * 64 + w * 16;
    const int cb = blockIdx.y * 128;

    stage_w(W, 512, cb, bsm, threadIdx.x);
    __syncthreads();

    f32x4 acc[8] = {};
    const float* Ap = A + (size_t)(m0 + l16) * K + 8 * g;
    const int xorv = (l16 & 7) << 4;
    const char* bsb = reinterpret_cast<const char*>(bsm);

    #pragma unroll
    for (int ks = 0; ks < K; ks += 32) {
        float4 af0 = *reinterpret_cast<const float4*>(Ap + ks);
        float4 af1 = *reinterpret_cast<const float4*>(Ap + ks + 4);
        short8 a;
        a[0] = (short)f2bf_u(af0.x); a[1] = (short)f2bf_u(af0.y);
        a[2] = (short)f2bf_u(af0.z); a[3] = (short)f2bf_u(af0.w);
        a[4] = (short)f2bf_u(af1.x); a[5] = (short)f2bf_u(af1.y);
        a[6] = (short)f2bf_u(af1.z); a[7] = (short)f2bf_u(af1.w);
        #pragma unroll
        for (int c = 0; c < 8; ++c) {
            int a0 = (c * 16 + l16) * 512 + (ks + 8 * g) * 2;
            short8 b = *reinterpret_cast<const short8*>(bsb + (a0 ^ xorv));
            acc[c] = __builtin_amdgcn_mfma_f32_16x16x32_bf16(a, b, acc[c], 0, 0, 0);
        }
    }

    if (blockIdx.y < 2) {
        // r-part, unit layout, pre-scaled
        #pragma unroll
        for (int c = 0; c < 8; ++c) {
            int col = cb + c * 16 + l16;        // 0..255
            int h = col >> 5, d = col & 31;
            #pragma unroll
            for (int r = 0; r < 4; ++r) {
                int row = m0 + 4 * g + r;
                int bb = row >> 11, n = row & 2047;
                size_t base = (size_t)(bb * 8 + h) * 65536;
                int unit = ((n >> 5) * 4 + (d >> 4) * 2 + ((d >> 3) & 1)) * 32 + (n & 31);
                R[base + (size_t)unit * 8 + (d & 7)] = f2bf_u(acc[c][r] * RSQ);
            }
        }
    } else {
        // v-part, permuted unit layout; 4 consecutive n -> contiguous e run
        #pragma unroll
        for (int c = 0; c < 8; ++c) {
            int colp = cb - 256 + c * 16 + l16; // 0..255
            int h = colp >> 5, d = colp & 31;
            int row = m0 + 4 * g;
            int bb = row >> 11, n = row & 2047;
            size_t base = (size_t)(bb * 8 + h) * 65536;
            int nl = n & 31;
            int vh = nl >> 4, r4 = nl & 15;
            int hi2 = (r4 >> 2) & 1;
            int e0 = (r4 & 3) + 4 * (r4 >> 3);
            int unit = ((n >> 5) * 4 + vh * 2 + hi2) * 32 + d;
            ushort4 s;
            s.x = f2bf_u(acc[c][0]); s.y = f2bf_u(acc[c][1]);
            s.z = f2bf_u(acc[c][2]); s.w = f2bf_u(acc[c][3]);
            *reinterpret_cast<ushort4*>(Vt + base + (size_t)unit * 8 + e0) = s;
        }
    }
}

// ---------- flash attention: 32x32x16 MFMA, K+V LDS-staged, full 2048 kv per block ----------
// 256 blocks (XCD-bijective): stream(dir,bh) x 8 qblk. 8 waves/block, 32 q-rows/wave.
// 16 tiles x 128 kv, double-buffered; 4 compute steps + one __syncthreads per tile.
// Writes one partial acc (bf16) + l (f32) per q-row; normalized in gemm_out.
__global__ __launch_bounds__(512, 4) void attn_kernel(
    const ushort_t* __restrict__ rU_sed, const ushort_t* __restrict__ rU_doa,
    const ushort_t* __restrict__ vU_sed, const ushort_t* __restrict__ vU_doa,
    ushort_t* __restrict__ part,   // [stream*2048 + q][32 d] bf16
    float* __restrict__ lpart) {   // [stream*2048 + q] f32
    __shared__ __align__(16) ushort_t smem[16384];   // 2 bufs x (K 8KB | V 8KB)

    const int bid = blockIdx.x;                // 0..255
    const int xcd = bid & 7, i = bid >> 3;     // i 0..31
    const int stream = xcd * 4 + (i & 3);      // 0..31
    const int qblk = i >> 2;                   // 0..7
    const int dir = stream >> 4, bh = stream & 15;

    const ushort_t* rQ = dir ? rU_doa : rU_sed;
    const ushort_t* rK = dir ? rU_sed : rU_doa;
    const ushort_t* vV = dir ? vU_sed : vU_doa;

    const int tid = threadIdx.x;
    const int w = tid >> 6, lane = tid & 63;
    const int l31 = lane & 31, hi = lane >> 5;
    const size_t sB = (size_t)bh * 65536;
    const int qbase = qblk * 256 + w * 32;

    // Q B-frags (pre-scaled in gemm_in)
    const short8 qf0 = *reinterpret_cast<const short8*>(rQ + sB + (size_t)qbase * 32 + lane * 8);
    const short8 qf1 = *reinterpret_cast<const short8*>(rQ + sB + (size_t)qbase * 32 + 512 + lane * 8);

    const ushort_t* srcK = rK + sB + tid * 8;                // per-lane global source
    const ushort_t* srcV = vV + sB + tid * 8;
    const int dstK = w * 512;                                // wave-uniform LDS base
    const int dstV = 4096 + w * 512;

    f32x16 acc = {};
    f32x4 lv = {};

    auto stage = [&](int t, int bufsel) {
        GLD_LDS16(srcK + (size_t)t * 4096, &smem[bufsel * 8192 + dstK]);
        GLD_LDS16(srcV + (size_t)t * 4096, &smem[bufsel * 8192 + dstV]);
    };

    int buf = 0;
    stage(0, 0);
    __syncthreads();

    for (int t = 0; t < 16; ++t) {             // 16 tiles x 128 kv = full 2048
        if (t < 15) stage(t + 1, buf ^ 1);
        const ushort_t* KB = &smem[buf * 8192];
        const ushort_t* VB = &smem[buf * 8192 + 4096];
        #pragma unroll
        for (int s = 0; s < 4; ++s) {
            short8 kf0 = *reinterpret_cast<const short8*>(KB + s * 1024 + lane * 8);
            short8 kf1 = *reinterpret_cast<const short8*>(KB + s * 1024 + 512 + lane * 8);
            short8 vf0 = *reinterpret_cast<const short8*>(VB + s * 1024 + lane * 8);
            short8 vf1 = *reinterpret_cast<const short8*>(VB + s * 1024 + 512 + lane * 8);

            f32x16 z16 = {};
            f32x16 st = __builtin_amdgcn_mfma_f32_32x32x16_bf16(kf0, qf0, z16, 0, 0, 0);
            st = __builtin_amdgcn_mfma_f32_32x32x16_bf16(kf1, qf1, st, 0, 0, 0);

            float p[16];
            #pragma unroll
            for (int j = 0; j < 16; ++j) {
                p[j] = __builtin_amdgcn_exp2f(st[j]);
            }
            #pragma unroll
            for (int j = 0; j < 16; ++j) lv[j & 3] += p[j];

            unsigned pk[8];
            #pragma unroll
            for (int j = 0; j < 8; ++j) {
                asm("v_cvt_pk_bf16_f32 %0, %1, %2" : "=v"(pk[j]) : "v"(p[2 * j]), "v"(p[2 * j + 1]));
            }
            union { uint4v u; short8 s; } c1, c2;
            c1.u = uint4v{pk[0], pk[1], pk[2], pk[3]};
            c2.u = uint4v{pk[4], pk[5], pk[6], pk[7]};

            acc = __builtin_amdgcn_mfma_f32_32x32x16_bf16(vf0, c1.s, acc, 0, 0, 0);
            acc = __builtin_amdgcn_mfma_f32_32x32x16_bf16(vf1, c2.s, acc, 0, 0, 0);
        }
        __syncthreads();
        buf ^= 1;
    }

    // epilogue: l and partial acc
    float l = (lv[0] + lv[1]) + (lv[2] + lv[3]);
    l += __shfl_xor(l, 32);
    const int q = qbase + l31;
    const size_t prow = (size_t)stream * 2048 + q;
    if (lane < 32) lpart[prow] = l;
    ushort_t* pa = part + prow * 32;
    #pragma unroll
    for (int r = 0; r < 16; ++r) {
        int d = (r & 3) + 8 * (r >> 2) + 4 * hi;
        pa[d] = f2bf(acc[r]);
    }
}

// ---------- out-projection GEMM: fused W-transpose + normalize, 128-col tiles ----------
// A[row][k] = part(row, k) / l(row), built on the fly per k-chunk.
__global__ __launch_bounds__(256) void gemm_out_kernel(
    const ushort_t* __restrict__ part, const float* __restrict__ lpart,
    const float* __restrict__ W0, const float* __restrict__ W1,
    float* __restrict__ c0, float* __restrict__ c1,
    const float* __restrict__ bias0, const float* __restrict__ bias1) {
    __shared__ __align__(16) ushort_t bsm[32768];   // 64KB: [128 cols][256 k] bf16 swz
    const int z = blockIdx.z;
    const float* W = z ? W1 : W0;
    float* C = z ? c1 : c0;
    const float* bias = z ? bias1 : bias0;
    constexpr int N = 256;
    const int w = threadIdx.x >> 6, lane = threadIdx.x & 63;
    const int l16 = lane & 15, g = lane >> 4;
    const int m0 = blockIdx.x * 64 + w * 16;
    const int cb = blockIdx.y * 128;

    stage_w(W, 256, cb, bsm, threadIdx.x);
    __syncthreads();

    const int row = m0 + l16;
    const int bb = row >> 11, q = row & 2047;
    const int xorv = (l16 & 7) << 4;
    const char* bsb = reinterpret_cast<const char*>(bsm);

    f32x4 acc[8] = {};
    #pragma unroll
    for (int it = 0; it < 8; ++it) {           // it = head h, k-chunk base = it*32
        const int strm = z * 16 + bb * 8 + it;
        const size_t pr0 = (size_t)strm * 2048 + q;
        float inv = 1.0f / lpart[pr0];
        const ushort_t* p0 = part + pr0 * 32 + 8 * g;
        short8 pa = *reinterpret_cast<const short8*>(p0);
        short8 a;
        #pragma unroll
        for (int e = 0; e < 8; ++e) {
            a[e] = (short)f2bf_u(bf2f((ushort_t)pa[e]) * inv);
        }
        #pragma unroll
        for (int c = 0; c < 8; ++c) {
            int a0 = (c * 16 + l16) * 512 + (it * 32 + 8 * g) * 2;
            short8 b = *reinterpret_cast<const short8*>(bsb + (a0 ^ xorv));
            acc[c] = __builtin_amdgcn_mfma_f32_16x16x32_bf16(a, b, acc[c], 0, 0, 0);
        }
    }
    #pragma unroll
    for (int c = 0; c < 8; ++c) {
        int col = cb + c * 16 + l16;
        #pragma unroll
        for (int r = 0; r < 4; ++r) {
            int orow = m0 + 4 * g + r;
            C[(size_t)orow * N + col] = acc[c][r] + bias[col];
        }
    }
}

// ---------- launch ----------
extern "C" void kernel_launch(void* const* d_in, const int* in_sizes, int n_in,
                              void* d_out, int out_size, void* d_ws, size_t ws_size,
                              hipStream_t stream) {
    const float* x_sed     = (const float*)d_in[0];
    const float* x_doa     = (const float*)d_in[1];
    const float* W_sed_in  = (const float*)d_in[2];
    const float* W_doa_in  = (const float*)d_in[3];
    const float* W_sed_out = (const float*)d_in[4];
    const float* b_sed_out = (const float*)d_in[5];
    const float* W_doa_out = (const float*)d_in[6];
    const float* b_doa_out = (const float*)d_in[7];
    float* out = (float*)d_out;

    ushort_t* ws = (ushort_t*)d_ws;
    ushort_t* rU_sed = ws;                          // 16*65536 (unit layout)
    ushort_t* rU_doa = rU_sed + 1048576;
    ushort_t* vU_sed = rU_doa + 1048576;            // 16*65536 (permuted unit layout)
    ushort_t* vU_doa = vU_sed + 1048576;
    ushort_t* part   = vU_doa + 1048576;            // 32*2048*32 bf16 = 4MB
    float*    lpart  = (float*)(part + 2097152);    // 32*2048 f32 = 256KB
    // total ~12.5 MB of ws

    gemm_in_kernel<<<dim3(64, 4, 2), 256, 0, stream>>>(x_sed, x_doa, W_sed_in, W_doa_in,
                                                       rU_sed, rU_doa, vU_sed, vU_doa);
    attn_kernel<<<dim3(256), 512, 0, stream>>>(rU_sed, rU_doa, vU_sed, vU_doa, part, lpart);
    gemm_out_kernel<<<dim3(64, 2, 2), 256, 0, stream>>>(part, lpart, W_sed_out, W_doa_out,
                                                        out, out + 1048576, b_sed_out, b_doa_out);
}